// Round 8
// baseline (1172.702 us; speedup 1.0000x reference)
//
#include <hip/hip_runtime.h>

#define NTOK 16384
#define DMODEL 1024
#define DHID 4096
#define NEXP 8
#define CAP 512

typedef __attribute__((ext_vector_type(8))) short bfrag_t;
typedef __attribute__((ext_vector_type(4))) float ffrag_t;

__device__ __forceinline__ unsigned short f2bf(float f) {
  unsigned u = __float_as_uint(f);
  u += 0x7FFFu + ((u >> 16) & 1u);
  return (unsigned short)(u >> 16);
}

// gelu(x) = x * sigmoid(x*(1.5957691 + 0.071354814 x^2))  (exact tanh-form identity)
__device__ __forceinline__ float gelu_fast(float x) {
  float t = x * x;
  float z = x * fmaf(0.071354814f, t, 1.5957691f);
  float e = __expf(-z);
  return x * __builtin_amdgcn_rcpf(1.0f + e);
}

// ------------- transpose+convert: in [K,N] f32 -> out [N,K] bf16, 64x64 tiles -------------
__global__ __launch_bounds__(256) void k_trans64(const float* __restrict__ in,
                                                 unsigned short* __restrict__ out, int K, int N) {
  const size_t zb = blockIdx.z;
  in  += zb * (size_t)K * N;
  out += zb * (size_t)N * K;
  __shared__ float tile[64][65];
  const int n0 = blockIdx.x * 64, k0 = blockIdx.y * 64;
  const int tx = threadIdx.x & 63, ty = threadIdx.x >> 6;
#pragma unroll
  for (int i = 0; i < 16; ++i) {
    const int k = ty * 16 + i;
    tile[k][tx] = in[(size_t)(k0 + k) * N + n0 + tx];
  }
  __syncthreads();
  const int sx = threadIdx.x & 7, sy = threadIdx.x >> 3;
#pragma unroll
  for (int j = 0; j < 2; ++j) {
    const int n = sy + j * 32;
    uint4 v;
    v.x = (unsigned)f2bf(tile[sx * 8 + 0][n]) | ((unsigned)f2bf(tile[sx * 8 + 1][n]) << 16);
    v.y = (unsigned)f2bf(tile[sx * 8 + 2][n]) | ((unsigned)f2bf(tile[sx * 8 + 3][n]) << 16);
    v.z = (unsigned)f2bf(tile[sx * 8 + 4][n]) | ((unsigned)f2bf(tile[sx * 8 + 5][n]) << 16);
    v.w = (unsigned)f2bf(tile[sx * 8 + 6][n]) | ((unsigned)f2bf(tile[sx * 8 + 7][n]) << 16);
    *(uint4*)&out[(size_t)(n0 + n) * K + k0 + sx * 8] = v;
  }
}

// ---------------- router: probs[e][t] + fused x->bf16 conversion ----------------
__global__ __launch_bounds__(256) void k_router(const float* __restrict__ x, const float* __restrict__ gw,
                                                const float* __restrict__ gb, const float* __restrict__ temp,
                                                float* __restrict__ probs, unsigned short* __restrict__ xb) {
  __shared__ float gws[DMODEL * NEXP];
  for (int i = threadIdx.x; i < DMODEL * NEXP; i += 256) gws[i] = gw[i];
  __syncthreads();
  const int wave = threadIdx.x >> 6, lane = threadIdx.x & 63;
  const int t = blockIdx.x * 4 + wave;
  const float* xr = x + (size_t)t * DMODEL;
  unsigned short* xw = xb + (size_t)t * DMODEL;
  float acc[NEXP];
#pragma unroll
  for (int e = 0; e < NEXP; ++e) acc[e] = 0.f;
  for (int d = lane; d < DMODEL; d += 64) {
    float xv = xr[d];
    xw[d] = f2bf(xv);
#pragma unroll
    for (int e = 0; e < NEXP; ++e) acc[e] += xv * gws[d * NEXP + e];
  }
#pragma unroll
  for (int off = 32; off >= 1; off >>= 1) {
#pragma unroll
    for (int e = 0; e < NEXP; ++e) acc[e] += __shfl_xor(acc[e], off);
  }
  if (lane == 0) {
    float st = fmaxf(temp[0], 0.1f);
    float m = -1e30f;
#pragma unroll
    for (int e = 0; e < NEXP; ++e) { acc[e] = (acc[e] + gb[e]) / st; m = fmaxf(m, acc[e]); }
    float s = 0.f;
#pragma unroll
    for (int e = 0; e < NEXP; ++e) { acc[e] = expf(acc[e] - m); s += acc[e]; }
    float inv = 1.f / s;
#pragma unroll
    for (int e = 0; e < NEXP; ++e) probs[(size_t)e * NTOK + t] = acc[e] * inv;
  }
}

// ---------------- exact top-512 per expert (radix select, tie -> lowest index) ----------------
__global__ __launch_bounds__(256) void k_topk(const float* __restrict__ probs, int* __restrict__ tok,
                                              float* __restrict__ scores, int* __restrict__ eqbuf) {
  const int e = blockIdx.x;
  const float* p = probs + (size_t)e * NTOK;
  int* eq = eqbuf + (size_t)e * NTOK;
  __shared__ int hist[256];
  __shared__ unsigned sh_pref;
  __shared__ int sh_k, sh_gt, sh_eq, sh_cnt;
  const int tid = threadIdx.x;
  if (tid == 0) { sh_pref = 0u; sh_k = CAP; }
  __syncthreads();
  for (int pass = 3; pass >= 0; --pass) {
    hist[tid] = 0;
    __syncthreads();
    const unsigned pref = sh_pref;
    const int shift = pass * 8;
    for (int t = tid; t < NTOK; t += 256) {
      unsigned key = __float_as_uint(p[t]);
      bool cand = (pass == 3) || ((key >> (shift + 8)) == pref);
      if (cand) atomicAdd(&hist[(key >> shift) & 255], 1);
    }
    __syncthreads();
    if (tid == 0) {
      int k = sh_k;
      int d = 255;
      while (hist[d] < k) { k -= hist[d]; --d; }
      sh_k = k;
      sh_pref = (pref << 8) | (unsigned)d;
    }
    __syncthreads();
  }
  const unsigned Kstar = sh_pref;
  const int need_eq = sh_k;
  if (tid == 0) { sh_gt = 0; sh_eq = 0; }
  __syncthreads();
  for (int t = tid; t < NTOK; t += 256) {
    unsigned key = __float_as_uint(p[t]);
    if (key > Kstar) {
      int pos = atomicAdd(&sh_gt, 1);
      tok[e * CAP + pos] = t;
      scores[e * CAP + pos] = p[t];
    } else if (key == Kstar) {
      int q = atomicAdd(&sh_eq, 1);
      eq[q] = t;
    }
  }
  __syncthreads();
  const int cg = sh_gt, ce = sh_eq;
  if (ce <= need_eq) {
    for (int j = tid; j < ce; j += 256) {
      tok[e * CAP + cg + j] = eq[j];
      scores[e * CAP + cg + j] = p[eq[j]];
    }
  } else {
    int lo = 0, hi = NTOK - 1;
    while (lo < hi) {
      int mid = (lo + hi) >> 1;
      if (tid == 0) sh_cnt = 0;
      __syncthreads();
      for (int j = tid; j < ce; j += 256)
        if (eq[j] <= mid) atomicAdd(&sh_cnt, 1);
      __syncthreads();
      if (sh_cnt >= need_eq) hi = mid; else lo = mid + 1;
      __syncthreads();
    }
    if (tid == 0) sh_cnt = 0;
    __syncthreads();
    for (int j = tid; j < ce; j += 256) {
      if (eq[j] <= lo) {
        int pos = cg + atomicAdd(&sh_cnt, 1);
        tok[e * CAP + pos] = eq[j];
        scores[e * CAP + pos] = p[eq[j]];
      }
    }
  }
}

// =====================================================================================
// 8-PHASE 256x256 GEMM (m201-style). BK=64, 8 waves (2Mx4N), dbuf 2x64KB, 4 phases per
// K-tile, 16 MFMA/phase, 2 gloads/phase, counted vmcnt(2) at ph0 & ph3, setprio.
// LDS buf: A 256rows x 128B @0, B @32768; byte slot sc (16B) of row r holds k-granule
// g = sc ^ (r&7) (read 2-way bank alias = free). Staging chunk j covers rows
// [64j,64j+64): thread slot L=j*512+tid, row=L>>3, coalesced 128B/8-lane source,
// LINEAR LDS dest. Chunk stage order per tile: B0B1@ph0 B2B3@ph1 A0A2@ph2 A1A3@ph3.
// vmcnt(2)@ph0 forces A1A3(t) (read ph1); vmcnt(2)@ph3 forces B*,A0,A2(t+1) (read
// t+1.ph0). Induction: exactly 2 loads outstanding after each wait. Never 0 mid-loop.
// =====================================================================================
#define WAITV2() asm volatile("s_waitcnt vmcnt(2)" ::: "memory")
#define WAITV0() asm volatile("s_waitcnt vmcnt(0)" ::: "memory")
#define BAR()                      \
  do {                             \
    asm volatile("" ::: "memory"); \
    __builtin_amdgcn_s_barrier();  \
    asm volatile("" ::: "memory"); \
  } while (0)

#define GL(SRC, DOFF)                                                          \
  __builtin_amdgcn_global_load_lds(                                            \
      (const __attribute__((address_space(1))) unsigned int*)(SRC),            \
      (__attribute__((address_space(3))) unsigned int*)(lds + (DOFF)), 16, 0, 0)

#define STG_A(J, T, NB) GL(gsA[J] + (size_t)(T) * 64, (NB) + (J) * 8192 + wave * 1024)
#define STG_B(J, T, NB) GL(gsB[J] + (size_t)(T) * 64, (NB) + 32768 + (J) * 8192 + wave * 1024)

#define RD_AF(X0, XK)                                                            \
  _Pragma("unroll") for (int _i = 0; _i < 4; ++_i)                               \
      af[_i] = *(const bfrag_t*)(base + (aoff[(X0) + _i] ^ (XK)))
#define RD_BF(XK)                                                                \
  _Pragma("unroll") for (int _n = 0; _n < 4; ++_n)                               \
      bf[_n] = *(const bfrag_t*)(base + (boff[_n] ^ (XK)))

#define MFMA16(MB)                                                                           \
  __builtin_amdgcn_s_setprio(1);                                                             \
  _Pragma("unroll") for (int _m = 0; _m < 4; ++_m) {                                         \
    _Pragma("unroll") for (int _n = 0; _n < 4; ++_n)                                         \
        acc[(MB) + _m][_n] = __builtin_amdgcn_mfma_f32_16x16x32_bf16(                        \
            af[_m], bf[_n], acc[(MB) + _m][_n], 0, 0, 0);                                    \
  }                                                                                          \
  __builtin_amdgcn_s_setprio(0)

// MODE 0: outB = bf16(gelu(v));  MODE 1: outF = v
template <int MODE>
__global__ __launch_bounds__(512, 2) void k_gemm8(
    const unsigned short* __restrict__ A, const unsigned short* __restrict__ Bt,
    const float* __restrict__ bias, float* __restrict__ outF, unsigned short* __restrict__ outB,
    int M, int N, int K) {
  // slab XCD swizzle
  const int gx = gridDim.x, gy = gridDim.y;
  const int nwg = gx * gy;
  const int id = blockIdx.x + blockIdx.y * gx;
  int bx, by;
  if ((gx & 7) == 0) {
    const int x = id & 7, c = id >> 3, H = gx >> 3;
    bx = x * H + (c % H);
    by = c / H;
  } else if ((nwg & 7) == 0) {
    const int q = nwg >> 3;
    const int sw = (id & 7) * q + (id >> 3);
    bx = sw % gx;
    by = sw / gx;
  } else {
    bx = blockIdx.x;
    by = blockIdx.y;
  }
  const int m0 = bx * 256, n0 = by * 256;

  const int tid = threadIdx.x, wave = tid >> 6, lane = tid & 63;
  const int wm = (wave >> 2) * 128;
  const int wn = (wave & 3) * 64;

  __shared__ alignas(16) char lds[131072];

  ffrag_t acc[8][4];
#pragma unroll
  for (int i = 0; i < 8; ++i)
#pragma unroll
    for (int j = 0; j < 4; ++j)
#pragma unroll
      for (int r = 0; r < 4; ++r) acc[i][j][r] = 0.f;

  // staging sources (coalesced: 8 lanes = one 128B row segment; source pre-permuted)
  const unsigned short* gsA[4];
  const unsigned short* gsB[4];
#pragma unroll
  for (int j = 0; j < 4; ++j) {
    const int L = j * 512 + tid;
    const int row = L >> 3;
    const int g = (L & 7) ^ (row & 7);
    gsA[j] = A + (size_t)(m0 + row) * K + g * 8;
    gsB[j] = Bt + (size_t)(n0 + row) * K + g * 8;
  }

  // read offsets (kk0); kk1 = ^64
  int aoff[8], boff[4];
#pragma unroll
  for (int mi = 0; mi < 8; ++mi) {
    const int row = wm + mi * 16 + (lane & 15);
    aoff[mi] = row * 128 + ((((lane >> 4)) ^ (row & 7)) << 4);
  }
#pragma unroll
  for (int ni = 0; ni < 4; ++ni) {
    const int row = wn + ni * 16 + (lane & 15);
    boff[ni] = 32768 + row * 128 + ((((lane >> 4)) ^ (row & 7)) << 4);
  }

  const int NT = K >> 6;

  // prologue: stage tile0 in canonical order (last two issued = A1,A3)
  STG_B(0, 0, 0); STG_B(1, 0, 0); STG_B(2, 0, 0); STG_B(3, 0, 0);
  STG_A(0, 0, 0); STG_A(2, 0, 0); STG_A(1, 0, 0); STG_A(3, 0, 0);
  WAITV2();
  BAR();

  bfrag_t af[4], bf[4];

  for (int t = 0; t < NT - 1; ++t) {
    const char* base = lds + ((t & 1) << 16);
    const int nb = ((t + 1) & 1) << 16;
    // ph0: kk0, mi0-3 (+ B reads)
    RD_AF(0, 0);
    RD_BF(0);
    STG_B(0, t + 1, nb); STG_B(1, t + 1, nb);
    WAITV2();
    BAR();
    MFMA16(0);
    BAR();
    // ph1: kk0, mi4-7
    RD_AF(4, 0);
    STG_B(2, t + 1, nb); STG_B(3, t + 1, nb);
    BAR();
    MFMA16(4);
    BAR();
    // ph2: kk1, mi0-3 (+ B reads)
    RD_AF(0, 64);
    RD_BF(64);
    STG_A(0, t + 1, nb); STG_A(2, t + 1, nb);
    BAR();
    MFMA16(0);
    BAR();
    // ph3: kk1, mi4-7
    RD_AF(4, 64);
    STG_A(1, t + 1, nb); STG_A(3, t + 1, nb);
    WAITV2();
    BAR();
    MFMA16(4);
    BAR();
  }
  {  // peeled last tile: no staging
    const char* base = lds + (((NT - 1) & 1) << 16);
    RD_AF(0, 0);
    RD_BF(0);
    WAITV0();
    BAR();
    MFMA16(0);
    BAR();
    RD_AF(4, 0);
    BAR();
    MFMA16(4);
    BAR();
    RD_AF(0, 64);
    RD_BF(64);
    BAR();
    MFMA16(0);
    BAR();
    RD_AF(4, 64);
    BAR();
    MFMA16(4);
    BAR();
  }

  const int rq = lane >> 4, cs = lane & 15;
  if (MODE == 0) {
    // LDS-bounce epilogue (wave-private 2304B regions), full-line bf16 stores
    float bv[4];
#pragma unroll
    for (int ni = 0; ni < 4; ++ni) bv[ni] = bias[n0 + wn + ni * 16 + cs];
    unsigned short* wbase = (unsigned short*)(lds + wave * 2304);
#pragma unroll
    for (int mi = 0; mi < 8; ++mi) {
#pragma unroll
      for (int ni = 0; ni < 4; ++ni)
#pragma unroll
        for (int r = 0; r < 4; ++r) {
          float v = acc[mi][ni][r] + bv[ni];
          wbase[(rq * 4 + r) * 72 + ni * 16 + cs] = f2bf(gelu_fast(v));
        }
      const int rrow = lane >> 3, uu = lane & 7;
      uint4 v0 = *(const uint4*)((const char*)wbase + rrow * 144 + uu * 16);
      uint4 v1 = *(const uint4*)((const char*)wbase + (rrow + 8) * 144 + uu * 16);
      *(uint4*)&outB[((size_t)m0 + wm + mi * 16 + rrow) * N + n0 + wn + uu * 8] = v0;
      *(uint4*)&outB[((size_t)m0 + wm + mi * 16 + rrow + 8) * N + n0 + wn + uu * 8] = v1;
    }
  } else {
#pragma unroll
    for (int ni = 0; ni < 4; ++ni) {
      const int n = n0 + wn + ni * 16 + cs;
      const float bv = bias[n];
#pragma unroll
      for (int mi = 0; mi < 8; ++mi)
#pragma unroll
        for (int r = 0; r < 4; ++r) {
          const int m = m0 + wm + mi * 16 + rq * 4 + r;
          outF[(size_t)m * N + n] = acc[mi][ni][r] + bv;
        }
    }
  }
}

// =====================================================================================
// m97-structure GEMM: 128x128, BK=64, 4 waves, single 32KB LDS, 5 blocks/CU (160KB).
// GATHER: A rows indirected via tok (fuses token gather into expert FFN-1).
// MODE 0: bf16(gelu) LDS-bounce; MODE 1: f32 overwrite; MODE 2: scaled atomic scatter.
// =====================================================================================
template <int MODE, bool GATHER>
__global__ __launch_bounds__(256, 5) void k_gemm(
    const unsigned short* __restrict__ A, const unsigned short* __restrict__ Bt,
    const float* __restrict__ bias, float* __restrict__ outF, unsigned short* __restrict__ outB,
    const int* __restrict__ tok, const float* __restrict__ scale,
    int M, int N, int Kloop, int LDK, int ksplit) {
  const int zb = blockIdx.z / ksplit;
  const int kc = blockIdx.z % ksplit;
  if (!GATHER) A += (size_t)zb * M * LDK;
  A += (size_t)kc * Kloop;
  Bt += (size_t)zb * N * LDK + (size_t)kc * Kloop;
  const float* bz = bias + (size_t)zb * N;

  const int gx = gridDim.x, gy = gridDim.y;
  const int nwg = gx * gy;
  const int id = blockIdx.x + blockIdx.y * gx;
  int bx, by;
  if ((gx & 7) == 0) {
    const int x = id & 7, c = id >> 3, H = gx >> 3;
    bx = x * H + (c % H);
    by = c / H;
  } else if ((nwg & 7) == 0) {
    const int q = nwg >> 3;
    const int sw = (id & 7) * q + (id >> 3);
    bx = sw % gx;
    by = sw / gx;
  } else {
    bx = blockIdx.x;
    by = blockIdx.y;
  }
  const int m0 = bx * 128, n0 = by * 128;

  const int tid = threadIdx.x, wave = tid >> 6, lane = tid & 63;
  const int wm = (wave >> 1) * 64, wn = (wave & 1) * 64;

  __shared__ alignas(16) unsigned short sh[128 * 128];
  unsigned short* As = sh;
  unsigned short* Bs = sh + 128 * 64;

  ffrag_t acc[4][4];
#pragma unroll
  for (int i = 0; i < 4; ++i)
#pragma unroll
    for (int j = 0; j < 4; ++j)
#pragma unroll
      for (int r = 0; r < 4; ++r) acc[i][j][r] = 0.f;

  int lb[4];
  const unsigned short* rowA[4];
  const unsigned short* rowB[4];
#pragma unroll
  for (int it = 0; it < 4; ++it) {
    int L = it * 256 + tid;
    int rr = L >> 3;
    int gg = (L & 7) ^ (rr & 7);
    lb[it] = (it * 256 + wave * 64) * 16;
    const unsigned short* ab =
        GATHER ? (A + (size_t)tok[zb * M + m0 + rr] * LDK) : (A + (size_t)(m0 + rr) * LDK);
    rowA[it] = ab + gg * 8;
    rowB[it] = Bt + (size_t)(n0 + rr) * LDK + gg * 8;
  }

  for (int kt = 0; kt < Kloop; kt += 64) {
#pragma unroll
    for (int it = 0; it < 4; ++it) {
      __builtin_amdgcn_global_load_lds(
          (const __attribute__((address_space(1))) unsigned int*)(rowA[it] + kt),
          (__attribute__((address_space(3))) unsigned int*)((char*)As + lb[it]), 16, 0, 0);
      __builtin_amdgcn_global_load_lds(
          (const __attribute__((address_space(1))) unsigned int*)(rowB[it] + kt),
          (__attribute__((address_space(3))) unsigned int*)((char*)Bs + lb[it]), 16, 0, 0);
    }
    __syncthreads();
#pragma unroll
    for (int kk = 0; kk < 2; ++kk) {
      bfrag_t af[4], bf[4];
      const int gl = kk * 4 + (lane >> 4);
#pragma unroll
      for (int mi = 0; mi < 4; ++mi) {
        int r = wm + mi * 16 + (lane & 15);
        af[mi] = *(const bfrag_t*)&As[r * 64 + ((gl ^ (r & 7)) * 8)];
      }
#pragma unroll
      for (int ni = 0; ni < 4; ++ni) {
        int r = wn + ni * 16 + (lane & 15);
        bf[ni] = *(const bfrag_t*)&Bs[r * 64 + ((gl ^ (r & 7)) * 8)];
      }
#pragma unroll
      for (int mi = 0; mi < 4; ++mi)
#pragma unroll
        for (int ni = 0; ni < 4; ++ni)
          acc[mi][ni] = __builtin_amdgcn_mfma_f32_16x16x32_bf16(af[mi], bf[ni], acc[mi][ni], 0, 0, 0);
    }
    __syncthreads();
  }

  const int rsub = (lane >> 4) * 4, cs = lane & 15;
  if (MODE == 0) {
    float bv[4];
#pragma unroll
    for (int ni = 0; ni < 4; ++ni) bv[ni] = bz[n0 + wn + ni * 16 + cs];
#pragma unroll
    for (int mi = 0; mi < 4; ++mi)
#pragma unroll
      for (int ni = 0; ni < 4; ++ni)
#pragma unroll
        for (int r = 0; r < 4; ++r) {
          float v = acc[mi][ni][r] + bv[ni];
          sh[(wm + mi * 16 + rsub + r) * 128 + (wn + ni * 16 + cs)] = f2bf(gelu_fast(v));
        }
    __syncthreads();
    const int seg = tid & 15, rw = tid >> 4;
#pragma unroll
    for (int rep = 0; rep < 8; ++rep) {
      const int row = rep * 16 + rw;
      uint4 v = *(const uint4*)&sh[row * 128 + seg * 8];
      *(uint4*)&outB[((size_t)zb * M + m0 + row) * N + n0 + seg * 8] = v;
    }
  } else if (MODE == 1) {
#pragma unroll
    for (int ni = 0; ni < 4; ++ni) {
      const int n = n0 + wn + ni * 16 + cs;
      const float bv = bz[n];
#pragma unroll
      for (int mi = 0; mi < 4; ++mi)
#pragma unroll
        for (int r = 0; r < 4; ++r) {
          const int m = m0 + wm + mi * 16 + rsub + r;
          outF[(size_t)m * N + n] = acc[mi][ni][r] + bv;
        }
    }
  } else {
#pragma unroll
    for (int ni = 0; ni < 4; ++ni) {
      const int n = n0 + wn + ni * 16 + cs;
      const float bv = (kc == 0) ? bz[n] : 0.f;
#pragma unroll
      for (int mi = 0; mi < 4; ++mi)
#pragma unroll
        for (int r = 0; r < 4; ++r) {
          const int m = m0 + wm + mi * 16 + rsub + r;
          const int t = tok[zb * M + m];
          const float s = scale[zb * M + m];
          atomicAdd(&outF[(size_t)t * N + n], (acc[mi][ni][r] + bv) * s);
        }
    }
  }
}

extern "C" void kernel_launch(void* const* d_in, const int* in_sizes, int n_in,
                              void* d_out, int out_size, void* d_ws, size_t ws_size,
                              hipStream_t stream) {
  const float* x      = (const float*)d_in[0];
  const float* gate_w = (const float*)d_in[1];
  const float* gate_b = (const float*)d_in[2];
  const float* temp   = (const float*)d_in[3];
  const float* sw1    = (const float*)d_in[4];
  const float* sb1    = (const float*)d_in[5];
  const float* sw2    = (const float*)d_in[6];
  const float* sb2    = (const float*)d_in[7];
  const float* ew1    = (const float*)d_in[8];
  const float* eb1    = (const float*)d_in[9];
  const float* ew2    = (const float*)d_in[10];
  const float* eb2    = (const float*)d_in[11];
  float* out = (float*)d_out;

  char* ws = (char*)d_ws;
  size_t o = 0;
  auto take = [&](size_t bytes) { char* p = ws + o; o += (bytes + 255) & ~(size_t)255; return p; };
  unsigned short* x_bf = (unsigned short*)take((size_t)NTOK * DMODEL * 2);
  unsigned short* w1t  = (unsigned short*)take((size_t)DMODEL * DHID * 2);
  unsigned short* w2t  = (unsigned short*)take((size_t)DHID * DMODEL * 2);
  unsigned short* ew1t = (unsigned short*)take((size_t)NEXP * DMODEL * DHID * 2);
  unsigned short* ew2t = (unsigned short*)take((size_t)NEXP * DHID * DMODEL * 2);
  float* probs         = (float*)take((size_t)NEXP * NTOK * 4);
  int* tok             = (int*)take((size_t)NEXP * CAP * 4);
  float* scores        = (float*)take((size_t)NEXP * CAP * 4);
  int* eqbuf           = (int*)take((size_t)NEXP * NTOK * 4);
  unsigned short* he   = (unsigned short*)take((size_t)NEXP * CAP * DHID * 2);
  unsigned short* hs   = (unsigned short*)take((size_t)NTOK * DHID * 2);

  // prep: weight transposes (full-line stores); x conversion fused into router
  k_trans64<<<dim3(DHID / 64, DMODEL / 64, 1), 256, 0, stream>>>(sw1, w1t, DMODEL, DHID);
  k_trans64<<<dim3(DMODEL / 64, DHID / 64, 1), 256, 0, stream>>>(sw2, w2t, DHID, DMODEL);
  k_trans64<<<dim3(DHID / 64, DMODEL / 64, NEXP), 256, 0, stream>>>(ew1, ew1t, DMODEL, DHID);
  k_trans64<<<dim3(DMODEL / 64, DHID / 64, NEXP), 256, 0, stream>>>(ew2, ew2t, DHID, DMODEL);

  // router (+ x->bf16) + top-k
  k_router<<<NTOK / 4, 256, 0, stream>>>(x, gate_w, gate_b, temp, probs, x_bf);
  k_topk<<<NEXP, 256, 0, stream>>>(probs, tok, scores, eqbuf);

  // shared FFN: GEMM-1 on the 8-phase 256^2 kernel; GEMM-2 on m97 kernel
  k_gemm8<0><<<dim3(NTOK / 256, DHID / 256, 1), 512, 0, stream>>>(
      x_bf, w1t, sb1, nullptr, hs, NTOK, DHID, DMODEL);
  k_gemm<1, false><<<dim3(128, 8, 1), 256, 0, stream>>>(
      hs, w2t, sb2, out, nullptr, nullptr, nullptr, NTOK, DMODEL, DHID, DHID, 1);

  // routed experts: FFN-1 with fused gather; FFN-2 scatter with K-split x4
  k_gemm<0, true><<<dim3(4, 32, NEXP), 256, 0, stream>>>(
      x_bf, ew1t, eb1, nullptr, he, tok, nullptr, CAP, DHID, DMODEL, DMODEL, 1);
  k_gemm<2, false><<<dim3(4, 8, NEXP * 4), 256, 0, stream>>>(
      he, ew2t, eb2, out, nullptr, tok, scores, CAP, DMODEL, DHID / 4, DHID, 4);
}

// Round 9
// 670.673 us; speedup vs baseline: 1.7485x; 1.7485x over previous
//
#include <hip/hip_runtime.h>

#define NTOK 16384
#define DMODEL 1024
#define DHID 4096
#define NEXP 8
#define CAP 512

typedef __attribute__((ext_vector_type(8))) short bfrag_t;
typedef __attribute__((ext_vector_type(4))) float ffrag_t;

__device__ __forceinline__ unsigned short f2bf(float f) {
  unsigned u = __float_as_uint(f);
  u += 0x7FFFu + ((u >> 16) & 1u);
  return (unsigned short)(u >> 16);
}

// gelu(x) = x * sigmoid(x*(1.5957691 + 0.071354814 x^2))  (exact tanh-form identity)
__device__ __forceinline__ float gelu_fast(float x) {
  float t = x * x;
  float z = x * fmaf(0.071354814f, t, 1.5957691f);
  float e = __expf(-z);
  return x * __builtin_amdgcn_rcpf(1.0f + e);
}

// ------------- transpose+convert: in [K,N] f32 -> out [N,K] bf16, 64x64 tiles -------------
__global__ __launch_bounds__(256) void k_trans64(const float* __restrict__ in,
                                                 unsigned short* __restrict__ out, int K, int N) {
  const size_t zb = blockIdx.z;
  in  += zb * (size_t)K * N;
  out += zb * (size_t)N * K;
  __shared__ float tile[64][65];
  const int n0 = blockIdx.x * 64, k0 = blockIdx.y * 64;
  const int tx = threadIdx.x & 63, ty = threadIdx.x >> 6;
#pragma unroll
  for (int i = 0; i < 16; ++i) {
    const int k = ty * 16 + i;
    tile[k][tx] = in[(size_t)(k0 + k) * N + n0 + tx];
  }
  __syncthreads();
  const int sx = threadIdx.x & 7, sy = threadIdx.x >> 3;
#pragma unroll
  for (int j = 0; j < 2; ++j) {
    const int n = sy + j * 32;
    uint4 v;
    v.x = (unsigned)f2bf(tile[sx * 8 + 0][n]) | ((unsigned)f2bf(tile[sx * 8 + 1][n]) << 16);
    v.y = (unsigned)f2bf(tile[sx * 8 + 2][n]) | ((unsigned)f2bf(tile[sx * 8 + 3][n]) << 16);
    v.z = (unsigned)f2bf(tile[sx * 8 + 4][n]) | ((unsigned)f2bf(tile[sx * 8 + 5][n]) << 16);
    v.w = (unsigned)f2bf(tile[sx * 8 + 6][n]) | ((unsigned)f2bf(tile[sx * 8 + 7][n]) << 16);
    *(uint4*)&out[(size_t)(n0 + n) * K + k0 + sx * 8] = v;
  }
}

// ---------------- router: probs[e][t] + fused x->bf16 conversion ----------------
__global__ __launch_bounds__(256) void k_router(const float* __restrict__ x, const float* __restrict__ gw,
                                                const float* __restrict__ gb, const float* __restrict__ temp,
                                                float* __restrict__ probs, unsigned short* __restrict__ xb) {
  __shared__ float gws[DMODEL * NEXP];
  for (int i = threadIdx.x; i < DMODEL * NEXP; i += 256) gws[i] = gw[i];
  __syncthreads();
  const int wave = threadIdx.x >> 6, lane = threadIdx.x & 63;
  const int t = blockIdx.x * 4 + wave;
  const float* xr = x + (size_t)t * DMODEL;
  unsigned short* xw = xb + (size_t)t * DMODEL;
  float acc[NEXP];
#pragma unroll
  for (int e = 0; e < NEXP; ++e) acc[e] = 0.f;
  for (int d = lane; d < DMODEL; d += 64) {
    float xv = xr[d];
    xw[d] = f2bf(xv);
#pragma unroll
    for (int e = 0; e < NEXP; ++e) acc[e] += xv * gws[d * NEXP + e];
  }
#pragma unroll
  for (int off = 32; off >= 1; off >>= 1) {
#pragma unroll
    for (int e = 0; e < NEXP; ++e) acc[e] += __shfl_xor(acc[e], off);
  }
  if (lane == 0) {
    float st = fmaxf(temp[0], 0.1f);
    float m = -1e30f;
#pragma unroll
    for (int e = 0; e < NEXP; ++e) { acc[e] = (acc[e] + gb[e]) / st; m = fmaxf(m, acc[e]); }
    float s = 0.f;
#pragma unroll
    for (int e = 0; e < NEXP; ++e) { acc[e] = expf(acc[e] - m); s += acc[e]; }
    float inv = 1.f / s;
#pragma unroll
    for (int e = 0; e < NEXP; ++e) probs[(size_t)e * NTOK + t] = acc[e] * inv;
  }
}

// ------- exact top-512 per expert (radix select, tie -> lowest index) + slot map -------
__global__ __launch_bounds__(256) void k_topk(const float* __restrict__ probs, int* __restrict__ tok,
                                              float* __restrict__ scores, int* __restrict__ eqbuf,
                                              int* __restrict__ slot) {
  const int e = blockIdx.x;
  const float* p = probs + (size_t)e * NTOK;
  int* eq = eqbuf + (size_t)e * NTOK;
  int* sl = slot + (size_t)e * NTOK;
  __shared__ int hist[256];
  __shared__ unsigned sh_pref;
  __shared__ int sh_k, sh_gt, sh_eq, sh_cnt;
  const int tid = threadIdx.x;
  for (int t = tid; t < NTOK; t += 256) sl[t] = -1;
  if (tid == 0) { sh_pref = 0u; sh_k = CAP; }
  __syncthreads();
  for (int pass = 3; pass >= 0; --pass) {
    hist[tid] = 0;
    __syncthreads();
    const unsigned pref = sh_pref;
    const int shift = pass * 8;
    for (int t = tid; t < NTOK; t += 256) {
      unsigned key = __float_as_uint(p[t]);
      bool cand = (pass == 3) || ((key >> (shift + 8)) == pref);
      if (cand) atomicAdd(&hist[(key >> shift) & 255], 1);
    }
    __syncthreads();
    if (tid == 0) {
      int k = sh_k;
      int d = 255;
      while (hist[d] < k) { k -= hist[d]; --d; }
      sh_k = k;
      sh_pref = (pref << 8) | (unsigned)d;
    }
    __syncthreads();
  }
  const unsigned Kstar = sh_pref;
  const int need_eq = sh_k;
  if (tid == 0) { sh_gt = 0; sh_eq = 0; }
  __syncthreads();
  for (int t = tid; t < NTOK; t += 256) {
    unsigned key = __float_as_uint(p[t]);
    if (key > Kstar) {
      int pos = atomicAdd(&sh_gt, 1);
      tok[e * CAP + pos] = t;
      scores[e * CAP + pos] = p[t];
      sl[t] = pos;
    } else if (key == Kstar) {
      int q = atomicAdd(&sh_eq, 1);
      eq[q] = t;
    }
  }
  __syncthreads();
  const int cg = sh_gt, ce = sh_eq;
  if (ce <= need_eq) {
    for (int j = tid; j < ce; j += 256) {
      tok[e * CAP + cg + j] = eq[j];
      scores[e * CAP + cg + j] = p[eq[j]];
      sl[eq[j]] = cg + j;
    }
  } else {
    int lo = 0, hi = NTOK - 1;
    while (lo < hi) {
      int mid = (lo + hi) >> 1;
      if (tid == 0) sh_cnt = 0;
      __syncthreads();
      for (int j = tid; j < ce; j += 256)
        if (eq[j] <= mid) atomicAdd(&sh_cnt, 1);
      __syncthreads();
      if (sh_cnt >= need_eq) hi = mid; else lo = mid + 1;
      __syncthreads();
    }
    if (tid == 0) sh_cnt = 0;
    __syncthreads();
    for (int j = tid; j < ce; j += 256) {
      if (eq[j] <= lo) {
        int pos = cg + atomicAdd(&sh_cnt, 1);
        tok[e * CAP + pos] = eq[j];
        scores[e * CAP + pos] = p[eq[j]];
        sl[eq[j]] = pos;
      }
    }
  }
}

// ---------------- combine: out[t] += sum over selecting experts of pe rows ----------------
// pe layout: [(e*2+kc)][CAP][DMODEL] f32, already score-scaled. Only selected tokens touched.
__global__ __launch_bounds__(256) void k_combine(const float* __restrict__ pe,
                                                 const int* __restrict__ slot,
                                                 float* __restrict__ out) {
  const int wave = threadIdx.x >> 6, lane = threadIdx.x & 63;
  const int t = blockIdx.x * 4 + wave;
  int sl[NEXP];
  bool any = false;
#pragma unroll
  for (int e = 0; e < NEXP; ++e) {
    sl[e] = slot[(size_t)e * NTOK + t];
    any = any || (sl[e] >= 0);
  }
  if (!any) return;  // wave-uniform branch
  float* orow = out + (size_t)t * DMODEL;
  float4 a[4];
#pragma unroll
  for (int i = 0; i < 4; ++i) a[i] = *(float4*)&orow[i * 256 + lane * 4];
#pragma unroll
  for (int e = 0; e < NEXP; ++e) {
    if (sl[e] >= 0) {
      const float* p0 = pe + (((size_t)e * 2 + 0) * CAP + sl[e]) * DMODEL;
      const float* p1 = pe + (((size_t)e * 2 + 1) * CAP + sl[e]) * DMODEL;
#pragma unroll
      for (int i = 0; i < 4; ++i) {
        float4 v0 = *(const float4*)&p0[i * 256 + lane * 4];
        float4 v1 = *(const float4*)&p1[i * 256 + lane * 4];
        a[i].x += v0.x + v1.x;
        a[i].y += v0.y + v1.y;
        a[i].z += v0.z + v1.z;
        a[i].w += v0.w + v1.w;
      }
    }
  }
#pragma unroll
  for (int i = 0; i < 4; ++i) *(float4*)&orow[i * 256 + lane * 4] = a[i];
}

// =====================================================================================
// m97-structure GEMM: 128x128, BK=64, 4 waves, single 32KB LDS, 4 blocks/CU (proven R7).
// GATHER: A rows indirected via tok (fuses token gather into expert FFN-1).
// MODE 0: bf16(gelu) LDS-bounce; MODE 1: f32 overwrite;
// MODE 3: dense score-scaled f32 partial store to outF[(zb*ksplit+kc)*M+m][n] (no atomics).
// =====================================================================================
template <int MODE, bool GATHER>
__global__ __launch_bounds__(256, 4) void k_gemm(
    const unsigned short* __restrict__ A, const unsigned short* __restrict__ Bt,
    const float* __restrict__ bias, float* __restrict__ outF, unsigned short* __restrict__ outB,
    const int* __restrict__ tok, const float* __restrict__ scale,
    int M, int N, int Kloop, int LDK, int ksplit) {
  const int zb = blockIdx.z / ksplit;
  const int kc = blockIdx.z % ksplit;
  if (!GATHER) A += (size_t)zb * M * LDK;
  A += (size_t)kc * Kloop;
  Bt += (size_t)zb * N * LDK + (size_t)kc * Kloop;
  const float* bz = bias + (size_t)zb * N;

  const int gx = gridDim.x, gy = gridDim.y;
  const int nwg = gx * gy;
  const int id = blockIdx.x + blockIdx.y * gx;
  int bx, by;
  if ((gx & 7) == 0) {
    const int x = id & 7, c = id >> 3, H = gx >> 3;
    bx = x * H + (c % H);
    by = c / H;
  } else if ((nwg & 7) == 0) {
    const int q = nwg >> 3;
    const int sw = (id & 7) * q + (id >> 3);
    bx = sw % gx;
    by = sw / gx;
  } else {
    bx = blockIdx.x;
    by = blockIdx.y;
  }
  const int m0 = bx * 128, n0 = by * 128;

  const int tid = threadIdx.x, wave = tid >> 6, lane = tid & 63;
  const int wm = (wave >> 1) * 64, wn = (wave & 1) * 64;

  __shared__ alignas(16) unsigned short sh[128 * 128];
  unsigned short* As = sh;
  unsigned short* Bs = sh + 128 * 64;

  ffrag_t acc[4][4];
#pragma unroll
  for (int i = 0; i < 4; ++i)
#pragma unroll
    for (int j = 0; j < 4; ++j)
#pragma unroll
      for (int r = 0; r < 4; ++r) acc[i][j][r] = 0.f;

  int lb[4];
  const unsigned short* rowA[4];
  const unsigned short* rowB[4];
#pragma unroll
  for (int it = 0; it < 4; ++it) {
    int L = it * 256 + tid;
    int rr = L >> 3;
    int gg = (L & 7) ^ (rr & 7);
    lb[it] = (it * 256 + wave * 64) * 16;
    const unsigned short* ab =
        GATHER ? (A + (size_t)tok[zb * M + m0 + rr] * LDK) : (A + (size_t)(m0 + rr) * LDK);
    rowA[it] = ab + gg * 8;
    rowB[it] = Bt + (size_t)(n0 + rr) * LDK + gg * 8;
  }

  for (int kt = 0; kt < Kloop; kt += 64) {
#pragma unroll
    for (int it = 0; it < 4; ++it) {
      __builtin_amdgcn_global_load_lds(
          (const __attribute__((address_space(1))) unsigned int*)(rowA[it] + kt),
          (__attribute__((address_space(3))) unsigned int*)((char*)As + lb[it]), 16, 0, 0);
      __builtin_amdgcn_global_load_lds(
          (const __attribute__((address_space(1))) unsigned int*)(rowB[it] + kt),
          (__attribute__((address_space(3))) unsigned int*)((char*)Bs + lb[it]), 16, 0, 0);
    }
    __syncthreads();
#pragma unroll
    for (int kk = 0; kk < 2; ++kk) {
      bfrag_t af[4], bf[4];
      const int gl = kk * 4 + (lane >> 4);
#pragma unroll
      for (int mi = 0; mi < 4; ++mi) {
        int r = wm + mi * 16 + (lane & 15);
        af[mi] = *(const bfrag_t*)&As[r * 64 + ((gl ^ (r & 7)) * 8)];
      }
#pragma unroll
      for (int ni = 0; ni < 4; ++ni) {
        int r = wn + ni * 16 + (lane & 15);
        bf[ni] = *(const bfrag_t*)&Bs[r * 64 + ((gl ^ (r & 7)) * 8)];
      }
#pragma unroll
      for (int mi = 0; mi < 4; ++mi)
#pragma unroll
        for (int ni = 0; ni < 4; ++ni)
          acc[mi][ni] = __builtin_amdgcn_mfma_f32_16x16x32_bf16(af[mi], bf[ni], acc[mi][ni], 0, 0, 0);
    }
    __syncthreads();
  }

  const int rsub = (lane >> 4) * 4, cs = lane & 15;
  if (MODE == 0) {
    float bv[4];
#pragma unroll
    for (int ni = 0; ni < 4; ++ni) bv[ni] = bz[n0 + wn + ni * 16 + cs];
#pragma unroll
    for (int mi = 0; mi < 4; ++mi)
#pragma unroll
      for (int ni = 0; ni < 4; ++ni)
#pragma unroll
        for (int r = 0; r < 4; ++r) {
          float v = acc[mi][ni][r] + bv[ni];
          sh[(wm + mi * 16 + rsub + r) * 128 + (wn + ni * 16 + cs)] = f2bf(gelu_fast(v));
        }
    __syncthreads();
    const int seg = tid & 15, rw = tid >> 4;
#pragma unroll
    for (int rep = 0; rep < 8; ++rep) {
      const int row = rep * 16 + rw;
      uint4 v = *(const uint4*)&sh[row * 128 + seg * 8];
      *(uint4*)&outB[((size_t)zb * M + m0 + row) * N + n0 + seg * 8] = v;
    }
  } else if (MODE == 1) {
#pragma unroll
    for (int ni = 0; ni < 4; ++ni) {
      const int n = n0 + wn + ni * 16 + cs;
      const float bv = bz[n];
#pragma unroll
      for (int mi = 0; mi < 4; ++mi)
#pragma unroll
        for (int r = 0; r < 4; ++r) {
          const int m = m0 + wm + mi * 16 + rsub + r;
          outF[(size_t)m * N + n] = acc[mi][ni][r] + bv;
        }
    }
  } else {  // MODE 3: dense score-scaled partial store
    float* po = outF + (size_t)blockIdx.z * M * N;
#pragma unroll
    for (int ni = 0; ni < 4; ++ni) {
      const int n = n0 + wn + ni * 16 + cs;
      const float bv = (kc == 0) ? bz[n] : 0.f;
#pragma unroll
      for (int mi = 0; mi < 4; ++mi)
#pragma unroll
        for (int r = 0; r < 4; ++r) {
          const int m = m0 + wm + mi * 16 + rsub + r;
          const float s = scale[zb * M + m];
          po[(size_t)m * N + n] = (acc[mi][ni][r] + bv) * s;
        }
    }
  }
}

extern "C" void kernel_launch(void* const* d_in, const int* in_sizes, int n_in,
                              void* d_out, int out_size, void* d_ws, size_t ws_size,
                              hipStream_t stream) {
  const float* x      = (const float*)d_in[0];
  const float* gate_w = (const float*)d_in[1];
  const float* gate_b = (const float*)d_in[2];
  const float* temp   = (const float*)d_in[3];
  const float* sw1    = (const float*)d_in[4];
  const float* sb1    = (const float*)d_in[5];
  const float* sw2    = (const float*)d_in[6];
  const float* sb2    = (const float*)d_in[7];
  const float* ew1    = (const float*)d_in[8];
  const float* eb1    = (const float*)d_in[9];
  const float* ew2    = (const float*)d_in[10];
  const float* eb2    = (const float*)d_in[11];
  float* out = (float*)d_out;

  char* ws = (char*)d_ws;
  size_t o = 0;
  auto take = [&](size_t bytes) { char* p = ws + o; o += (bytes + 255) & ~(size_t)255; return p; };
  unsigned short* x_bf = (unsigned short*)take((size_t)NTOK * DMODEL * 2);
  unsigned short* w1t  = (unsigned short*)take((size_t)DMODEL * DHID * 2);
  unsigned short* w2t  = (unsigned short*)take((size_t)DHID * DMODEL * 2);
  unsigned short* ew1t = (unsigned short*)take((size_t)NEXP * DMODEL * DHID * 2);
  unsigned short* ew2t = (unsigned short*)take((size_t)NEXP * DHID * DMODEL * 2);
  float* probs         = (float*)take((size_t)NEXP * NTOK * 4);
  int* tok             = (int*)take((size_t)NEXP * CAP * 4);
  float* scores        = (float*)take((size_t)NEXP * CAP * 4);
  int* eqbuf           = (int*)take((size_t)NEXP * NTOK * 4);
  int* slot            = (int*)take((size_t)NEXP * NTOK * 4);
  float* pe            = (float*)take((size_t)NEXP * 2 * CAP * DMODEL * 4);
  unsigned short* he   = (unsigned short*)take((size_t)NEXP * CAP * DHID * 2);
  unsigned short* hs   = (unsigned short*)take((size_t)NTOK * DHID * 2);

  // prep: weight transposes; x conversion fused into router
  k_trans64<<<dim3(DHID / 64, DMODEL / 64, 1), 256, 0, stream>>>(sw1, w1t, DMODEL, DHID);
  k_trans64<<<dim3(DMODEL / 64, DHID / 64, 1), 256, 0, stream>>>(sw2, w2t, DHID, DMODEL);
  k_trans64<<<dim3(DHID / 64, DMODEL / 64, NEXP), 256, 0, stream>>>(ew1, ew1t, DMODEL, DHID);
  k_trans64<<<dim3(DMODEL / 64, DHID / 64, NEXP), 256, 0, stream>>>(ew2, ew2t, DHID, DMODEL);

  // router (+ x->bf16) + top-k (+ slot map)
  k_router<<<NTOK / 4, 256, 0, stream>>>(x, gate_w, gate_b, temp, probs, x_bf);
  k_topk<<<NEXP, 256, 0, stream>>>(probs, tok, scores, eqbuf, slot);

  // shared FFN (m97 kernels, 4 blocks/CU)
  k_gemm<0, false><<<dim3(128, 32, 1), 256, 0, stream>>>(
      x_bf, w1t, sb1, nullptr, hs, nullptr, nullptr, NTOK, DHID, DMODEL, DMODEL, 1);
  k_gemm<1, false><<<dim3(128, 8, 1), 256, 0, stream>>>(
      hs, w2t, sb2, out, nullptr, nullptr, nullptr, NTOK, DMODEL, DHID, DHID, 1);

  // routed experts: FFN-1 with fused gather; FFN-2 dense scaled partials (no atomics)
  k_gemm<0, true><<<dim3(4, 32, NEXP), 256, 0, stream>>>(
      x_bf, ew1t, eb1, nullptr, he, tok, nullptr, CAP, DHID, DMODEL, DMODEL, 1);
  k_gemm<3, false><<<dim3(4, 8, NEXP * 2), 256, 0, stream>>>(
      he, ew2t, eb2, pe, nullptr, nullptr, scores, CAP, DMODEL, DHID / 2, DHID, 2);

  // combine selected tokens into out
  k_combine<<<NTOK / 4, 256, 0, stream>>>(pe, slot, out);
}

// Round 11
// 651.322 us; speedup vs baseline: 1.8005x; 1.0297x over previous
//
#include <hip/hip_runtime.h>

#define NTOK 16384
#define DMODEL 1024
#define DHID 4096
#define NEXP 8
#define CAP 512

typedef __attribute__((ext_vector_type(8))) short bfrag_t;
typedef __attribute__((ext_vector_type(4))) float ffrag_t;
typedef __attribute__((ext_vector_type(4))) unsigned int u32x4;

__device__ __forceinline__ unsigned short f2bf(float f) {
  unsigned u = __float_as_uint(f);
  u += 0x7FFFu + ((u >> 16) & 1u);
  return (unsigned short)(u >> 16);
}

// gelu(x) = x * sigmoid(x*(1.5957691 + 0.071354814 x^2))  (exact tanh-form identity)
__device__ __forceinline__ float gelu_fast(float x) {
  float t = x * x;
  float z = x * fmaf(0.071354814f, t, 1.5957691f);
  float e = __expf(-z);
  return x * __builtin_amdgcn_rcpf(1.0f + e);
}

// ---- transpose+convert, dual-source batched: z==0 -> shared weight, z>0 -> expert z-1 ----
__global__ __launch_bounds__(256) void k_trans64d(const float* __restrict__ s_in,
                                                  const float* __restrict__ e_in,
                                                  unsigned short* __restrict__ s_out,
                                                  unsigned short* __restrict__ e_out,
                                                  int K, int N) {
  const int zb = blockIdx.z;
  const float* in;
  unsigned short* out;
  if (zb == 0) {
    in = s_in;
    out = s_out;
  } else {
    in = e_in + (size_t)(zb - 1) * K * N;
    out = e_out + (size_t)(zb - 1) * N * K;
  }
  __shared__ float tile[64][65];
  const int n0 = blockIdx.x * 64, k0 = blockIdx.y * 64;
  const int tx = threadIdx.x & 63, ty = threadIdx.x >> 6;
#pragma unroll
  for (int i = 0; i < 16; ++i) {
    const int k = ty * 16 + i;
    tile[k][tx] = in[(size_t)(k0 + k) * N + n0 + tx];
  }
  __syncthreads();
  const int sx = threadIdx.x & 7, sy = threadIdx.x >> 3;
#pragma unroll
  for (int j = 0; j < 2; ++j) {
    const int n = sy + j * 32;
    u32x4 v;
    v.x = (unsigned)f2bf(tile[sx * 8 + 0][n]) | ((unsigned)f2bf(tile[sx * 8 + 1][n]) << 16);
    v.y = (unsigned)f2bf(tile[sx * 8 + 2][n]) | ((unsigned)f2bf(tile[sx * 8 + 3][n]) << 16);
    v.z = (unsigned)f2bf(tile[sx * 8 + 4][n]) | ((unsigned)f2bf(tile[sx * 8 + 5][n]) << 16);
    v.w = (unsigned)f2bf(tile[sx * 8 + 6][n]) | ((unsigned)f2bf(tile[sx * 8 + 7][n]) << 16);
    *(u32x4*)&out[(size_t)(n0 + n) * K + k0 + sx * 8] = v;
  }
}

// ---------------- router: probs[e][t] + fused x->bf16 conversion ----------------
__global__ __launch_bounds__(256) void k_router(const float* __restrict__ x, const float* __restrict__ gw,
                                                const float* __restrict__ gb, const float* __restrict__ temp,
                                                float* __restrict__ probs, unsigned short* __restrict__ xb) {
  __shared__ float gws[DMODEL * NEXP];
  for (int i = threadIdx.x; i < DMODEL * NEXP; i += 256) gws[i] = gw[i];
  __syncthreads();
  const int wave = threadIdx.x >> 6, lane = threadIdx.x & 63;
  const int t = blockIdx.x * 4 + wave;
  const float* xr = x + (size_t)t * DMODEL;
  unsigned short* xw = xb + (size_t)t * DMODEL;
  float acc[NEXP];
#pragma unroll
  for (int e = 0; e < NEXP; ++e) acc[e] = 0.f;
  for (int d = lane; d < DMODEL; d += 64) {
    float xv = xr[d];
    xw[d] = f2bf(xv);
#pragma unroll
    for (int e = 0; e < NEXP; ++e) acc[e] += xv * gws[d * NEXP + e];
  }
#pragma unroll
  for (int off = 32; off >= 1; off >>= 1) {
#pragma unroll
    for (int e = 0; e < NEXP; ++e) acc[e] += __shfl_xor(acc[e], off);
  }
  if (lane == 0) {
    float st = fmaxf(temp[0], 0.1f);
    float m = -1e30f;
#pragma unroll
    for (int e = 0; e < NEXP; ++e) { acc[e] = (acc[e] + gb[e]) / st; m = fmaxf(m, acc[e]); }
    float s = 0.f;
#pragma unroll
    for (int e = 0; e < NEXP; ++e) { acc[e] = expf(acc[e] - m); s += acc[e]; }
    float inv = 1.f / s;
#pragma unroll
    for (int e = 0; e < NEXP; ++e) probs[(size_t)e * NTOK + t] = acc[e] * inv;
  }
}

// ------- exact top-512 per expert (radix select, tie -> lowest index) + slot map -------
__global__ __launch_bounds__(256) void k_topk(const float* __restrict__ probs, int* __restrict__ tok,
                                              float* __restrict__ scores, int* __restrict__ eqbuf,
                                              int* __restrict__ slot) {
  const int e = blockIdx.x;
  const float* p = probs + (size_t)e * NTOK;
  int* eq = eqbuf + (size_t)e * NTOK;
  int* sl = slot + (size_t)e * NTOK;
  __shared__ int hist[256];
  __shared__ unsigned sh_pref;
  __shared__ int sh_k, sh_gt, sh_eq, sh_cnt;
  const int tid = threadIdx.x;
  for (int t = tid; t < NTOK; t += 256) sl[t] = -1;
  if (tid == 0) { sh_pref = 0u; sh_k = CAP; }
  __syncthreads();
  for (int pass = 3; pass >= 0; --pass) {
    hist[tid] = 0;
    __syncthreads();
    const unsigned pref = sh_pref;
    const int shift = pass * 8;
    for (int t = tid; t < NTOK; t += 256) {
      unsigned key = __float_as_uint(p[t]);
      bool cand = (pass == 3) || ((key >> (shift + 8)) == pref);
      if (cand) atomicAdd(&hist[(key >> shift) & 255], 1);
    }
    __syncthreads();
    if (tid == 0) {
      int k = sh_k;
      int d = 255;
      while (hist[d] < k) { k -= hist[d]; --d; }
      sh_k = k;
      sh_pref = (pref << 8) | (unsigned)d;
    }
    __syncthreads();
  }
  const unsigned Kstar = sh_pref;
  const int need_eq = sh_k;
  if (tid == 0) { sh_gt = 0; sh_eq = 0; }
  __syncthreads();
  for (int t = tid; t < NTOK; t += 256) {
    unsigned key = __float_as_uint(p[t]);
    if (key > Kstar) {
      int pos = atomicAdd(&sh_gt, 1);
      tok[e * CAP + pos] = t;
      scores[e * CAP + pos] = p[t];
      sl[t] = pos;
    } else if (key == Kstar) {
      int q = atomicAdd(&sh_eq, 1);
      eq[q] = t;
    }
  }
  __syncthreads();
  const int cg = sh_gt, ce = sh_eq;
  if (ce <= need_eq) {
    for (int j = tid; j < ce; j += 256) {
      tok[e * CAP + cg + j] = eq[j];
      scores[e * CAP + cg + j] = p[eq[j]];
      sl[eq[j]] = cg + j;
    }
  } else {
    int lo = 0, hi = NTOK - 1;
    while (lo < hi) {
      int mid = (lo + hi) >> 1;
      if (tid == 0) sh_cnt = 0;
      __syncthreads();
      for (int j = tid; j < ce; j += 256)
        if (eq[j] <= mid) atomicAdd(&sh_cnt, 1);
      __syncthreads();
      if (sh_cnt >= need_eq) hi = mid; else lo = mid + 1;
      __syncthreads();
    }
    if (tid == 0) sh_cnt = 0;
    __syncthreads();
    for (int j = tid; j < ce; j += 256) {
      if (eq[j] <= lo) {
        int pos = cg + atomicAdd(&sh_cnt, 1);
        tok[e * CAP + pos] = eq[j];
        scores[e * CAP + pos] = p[eq[j]];
        sl[eq[j]] = pos;
      }
    }
  }
}

// =====================================================================================
// m97-structure GEMM: 128x128, BK=64, 4 waves, single 32KB LDS, 4 blocks/CU.
// GATHER: A rows indirected via tok (fused token gather).
// MODE 0: bf16(gelu) LDS-bounce (NT selects non-temporal stores);
// MODE 3: dense score-scaled f32 partial store (cached — consumed immediately);
// MODE 4: shared output + fused routed combine from pe via slot map, nt stores.
//   MODE 4 reuses params: tok -> slot[NEXP][NTOK], scale -> pe[(e*2+kc)][CAP][DMODEL].
// =====================================================================================
template <int MODE, bool GATHER, bool NT>
__global__ __launch_bounds__(256, 4) void k_gemm(
    const unsigned short* __restrict__ A, const unsigned short* __restrict__ Bt,
    const float* __restrict__ bias, float* __restrict__ outF, unsigned short* __restrict__ outB,
    const int* __restrict__ tok, const float* __restrict__ scale,
    int M, int N, int Kloop, int LDK, int ksplit) {
  const int zb = blockIdx.z / ksplit;
  const int kc = blockIdx.z % ksplit;
  if (!GATHER) A += (size_t)zb * M * LDK;
  A += (size_t)kc * Kloop;
  Bt += (size_t)zb * N * LDK + (size_t)kc * Kloop;
  const float* bz = bias + (size_t)zb * N;

  const int gx = gridDim.x, gy = gridDim.y;
  const int nwg = gx * gy;
  const int id = blockIdx.x + blockIdx.y * gx;
  int bx, by;
  if ((gx & 7) == 0) {
    const int x = id & 7, c = id >> 3, H = gx >> 3;
    bx = x * H + (c % H);
    by = c / H;
  } else if ((nwg & 7) == 0) {
    const int q = nwg >> 3;
    const int sw = (id & 7) * q + (id >> 3);
    bx = sw % gx;
    by = sw / gx;
  } else {
    bx = blockIdx.x;
    by = blockIdx.y;
  }
  const int m0 = bx * 128, n0 = by * 128;

  const int tid = threadIdx.x, wave = tid >> 6, lane = tid & 63;
  const int wm = (wave >> 1) * 64, wn = (wave & 1) * 64;

  __shared__ alignas(16) unsigned short sh[128 * 128];
  unsigned short* As = sh;
  unsigned short* Bs = sh + 128 * 64;

  ffrag_t acc[4][4];
#pragma unroll
  for (int i = 0; i < 4; ++i)
#pragma unroll
    for (int j = 0; j < 4; ++j)
#pragma unroll
      for (int r = 0; r < 4; ++r) acc[i][j][r] = 0.f;

  int lb[4];
  const unsigned short* rowA[4];
  const unsigned short* rowB[4];
#pragma unroll
  for (int it = 0; it < 4; ++it) {
    int L = it * 256 + tid;
    int rr = L >> 3;
    int gg = (L & 7) ^ (rr & 7);
    lb[it] = (it * 256 + wave * 64) * 16;
    const unsigned short* ab =
        GATHER ? (A + (size_t)tok[zb * M + m0 + rr] * LDK) : (A + (size_t)(m0 + rr) * LDK);
    rowA[it] = ab + gg * 8;
    rowB[it] = Bt + (size_t)(n0 + rr) * LDK + gg * 8;
  }

  for (int kt = 0; kt < Kloop; kt += 64) {
#pragma unroll
    for (int it = 0; it < 4; ++it) {
      __builtin_amdgcn_global_load_lds(
          (const __attribute__((address_space(1))) unsigned int*)(rowA[it] + kt),
          (__attribute__((address_space(3))) unsigned int*)((char*)As + lb[it]), 16, 0, 0);
      __builtin_amdgcn_global_load_lds(
          (const __attribute__((address_space(1))) unsigned int*)(rowB[it] + kt),
          (__attribute__((address_space(3))) unsigned int*)((char*)Bs + lb[it]), 16, 0, 0);
    }
    __syncthreads();
#pragma unroll
    for (int kk = 0; kk < 2; ++kk) {
      bfrag_t af[4], bf[4];
      const int gl = kk * 4 + (lane >> 4);
#pragma unroll
      for (int mi = 0; mi < 4; ++mi) {
        int r = wm + mi * 16 + (lane & 15);
        af[mi] = *(const bfrag_t*)&As[r * 64 + ((gl ^ (r & 7)) * 8)];
      }
#pragma unroll
      for (int ni = 0; ni < 4; ++ni) {
        int r = wn + ni * 16 + (lane & 15);
        bf[ni] = *(const bfrag_t*)&Bs[r * 64 + ((gl ^ (r & 7)) * 8)];
      }
#pragma unroll
      for (int mi = 0; mi < 4; ++mi)
#pragma unroll
        for (int ni = 0; ni < 4; ++ni)
          acc[mi][ni] = __builtin_amdgcn_mfma_f32_16x16x32_bf16(af[mi], bf[ni], acc[mi][ni], 0, 0, 0);
    }
    __syncthreads();
  }

  const int rsub = (lane >> 4) * 4, cs = lane & 15;
  if (MODE == 0) {
    float bv[4];
#pragma unroll
    for (int ni = 0; ni < 4; ++ni) bv[ni] = bz[n0 + wn + ni * 16 + cs];
#pragma unroll
    for (int mi = 0; mi < 4; ++mi)
#pragma unroll
      for (int ni = 0; ni < 4; ++ni)
#pragma unroll
        for (int r = 0; r < 4; ++r) {
          float v = acc[mi][ni][r] + bv[ni];
          sh[(wm + mi * 16 + rsub + r) * 128 + (wn + ni * 16 + cs)] = f2bf(gelu_fast(v));
        }
    __syncthreads();
    const int seg = tid & 15, rw = tid >> 4;
#pragma unroll
    for (int rep = 0; rep < 8; ++rep) {
      const int row = rep * 16 + rw;
      u32x4 v = *(const u32x4*)&sh[row * 128 + seg * 8];
      u32x4* dst = (u32x4*)&outB[((size_t)zb * M + m0 + row) * N + n0 + seg * 8];
      if (NT)
        __builtin_nontemporal_store(v, dst);
      else
        *dst = v;
    }
  } else if (MODE == 3) {  // dense score-scaled partial store (cached)
    float* po = outF + (size_t)blockIdx.z * M * N;
#pragma unroll
    for (int ni = 0; ni < 4; ++ni) {
      const int n = n0 + wn + ni * 16 + cs;
      const float bv = (kc == 0) ? bz[n] : 0.f;
#pragma unroll
      for (int mi = 0; mi < 4; ++mi)
#pragma unroll
        for (int r = 0; r < 4; ++r) {
          const int m = m0 + wm + mi * 16 + rsub + r;
          const float s = scale[zb * M + m];
          po[(size_t)m * N + n] = (acc[mi][ni][r] + bv) * s;
        }
    }
  } else {  // MODE 4: shared + fused routed combine, nt stores
    const int* slot = tok;
    const float* pe = scale;
    float bv[4];
#pragma unroll
    for (int ni = 0; ni < 4; ++ni) bv[ni] = bz[n0 + wn + ni * 16 + cs];
#pragma unroll
    for (int mi = 0; mi < 4; ++mi) {
#pragma unroll
      for (int r = 0; r < 4; ++r) {
        const int m = m0 + wm + mi * 16 + rsub + r;
        float ex[4] = {0.f, 0.f, 0.f, 0.f};
#pragma unroll
        for (int e = 0; e < NEXP; ++e) {
          const int sl = slot[(size_t)e * NTOK + m];
          if (sl >= 0) {
            const float* p0 = pe + ((size_t)(e * 2 + 0) * CAP + sl) * DMODEL;
            const float* p1 = pe + ((size_t)(e * 2 + 1) * CAP + sl) * DMODEL;
#pragma unroll
            for (int ni = 0; ni < 4; ++ni) {
              const int n = n0 + wn + ni * 16 + cs;
              ex[ni] += p0[n] + p1[n];
            }
          }
        }
#pragma unroll
        for (int ni = 0; ni < 4; ++ni) {
          const int n = n0 + wn + ni * 16 + cs;
          __builtin_nontemporal_store(acc[mi][ni][r] + bv[ni] + ex[ni],
                                      &outF[(size_t)m * N + n]);
        }
      }
    }
  }
}

extern "C" void kernel_launch(void* const* d_in, const int* in_sizes, int n_in,
                              void* d_out, int out_size, void* d_ws, size_t ws_size,
                              hipStream_t stream) {
  const float* x      = (const float*)d_in[0];
  const float* gate_w = (const float*)d_in[1];
  const float* gate_b = (const float*)d_in[2];
  const float* temp   = (const float*)d_in[3];
  const float* sw1    = (const float*)d_in[4];
  const float* sb1    = (const float*)d_in[5];
  const float* sw2    = (const float*)d_in[6];
  const float* sb2    = (const float*)d_in[7];
  const float* ew1    = (const float*)d_in[8];
  const float* eb1    = (const float*)d_in[9];
  const float* ew2    = (const float*)d_in[10];
  const float* eb2    = (const float*)d_in[11];
  float* out = (float*)d_out;

  char* ws = (char*)d_ws;
  size_t o = 0;
  auto take = [&](size_t bytes) { char* p = ws + o; o += (bytes + 255) & ~(size_t)255; return p; };
  unsigned short* x_bf = (unsigned short*)take((size_t)NTOK * DMODEL * 2);
  unsigned short* w1t  = (unsigned short*)take((size_t)DMODEL * DHID * 2);
  unsigned short* w2t  = (unsigned short*)take((size_t)DHID * DMODEL * 2);
  unsigned short* ew1t = (unsigned short*)take((size_t)NEXP * DMODEL * DHID * 2);
  unsigned short* ew2t = (unsigned short*)take((size_t)NEXP * DHID * DMODEL * 2);
  float* probs         = (float*)take((size_t)NEXP * NTOK * 4);
  int* tok             = (int*)take((size_t)NEXP * CAP * 4);
  float* scores        = (float*)take((size_t)NEXP * CAP * 4);
  int* eqbuf           = (int*)take((size_t)NEXP * NTOK * 4);
  int* slot            = (int*)take((size_t)NEXP * NTOK * 4);
  float* pe            = (float*)take((size_t)NEXP * 2 * CAP * DMODEL * 4);
  unsigned short* he   = (unsigned short*)take((size_t)NEXP * CAP * DHID * 2);
  unsigned short* hs   = (unsigned short*)take((size_t)NTOK * DHID * 2);

  // prep: batched weight transposes (2 launches); x conversion fused into router
  k_trans64d<<<dim3(DHID / 64, DMODEL / 64, 1 + NEXP), 256, 0, stream>>>(
      sw1, ew1, w1t, ew1t, DMODEL, DHID);
  k_trans64d<<<dim3(DMODEL / 64, DHID / 64, 1 + NEXP), 256, 0, stream>>>(
      sw2, ew2, w2t, ew2t, DHID, DMODEL);

  // router (+ x->bf16) + top-k (+ slot map)
  k_router<<<NTOK / 4, 256, 0, stream>>>(x, gate_w, gate_b, temp, probs, x_bf);
  k_topk<<<NEXP, 256, 0, stream>>>(probs, tok, scores, eqbuf, slot);

  // shared FFN-1 (nt stores for hs: keep A/B operands resident in L3)
  k_gemm<0, false, true><<<dim3(128, 32, 1), 256, 0, stream>>>(
      x_bf, w1t, sb1, nullptr, hs, nullptr, nullptr, NTOK, DHID, DMODEL, DMODEL, 1);

  // routed experts: FFN-1 with fused gather (he cached — consumed next); FFN-2 partials
  k_gemm<0, true, false><<<dim3(4, 32, NEXP), 256, 0, stream>>>(
      x_bf, ew1t, eb1, nullptr, he, tok, nullptr, CAP, DHID, DMODEL, DMODEL, 1);
  k_gemm<3, false, false><<<dim3(4, 8, NEXP * 2), 256, 0, stream>>>(
      he, ew2t, eb2, pe, nullptr, nullptr, scores, CAP, DMODEL, DHID / 2, DHID, 2);

  // shared FFN-2 with fused routed combine (reads pe via slot map), nt out stores
  k_gemm<4, false, true><<<dim3(128, 8, 1), 256, 0, stream>>>(
      hs, w2t, sb2, out, nullptr, slot, pe, NTOK, DMODEL, DHID, DHID, 1);
}

// Round 12
// 612.067 us; speedup vs baseline: 1.9160x; 1.0641x over previous
//
#include <hip/hip_runtime.h>

#define NTOK 16384
#define DMODEL 1024
#define DHID 4096
#define NEXP 8
#define CAP 512

typedef __attribute__((ext_vector_type(8))) short bfrag_t;
typedef __attribute__((ext_vector_type(4))) float ffrag_t;
typedef __attribute__((ext_vector_type(4))) unsigned int u32x4;

__device__ __forceinline__ unsigned short f2bf(float f) {
  unsigned u = __float_as_uint(f);
  u += 0x7FFFu + ((u >> 16) & 1u);
  return (unsigned short)(u >> 16);
}

// gelu(x) = x * sigmoid(x*(1.5957691 + 0.071354814 x^2))  (exact tanh-form identity)
__device__ __forceinline__ float gelu_fast(float x) {
  float t = x * x;
  float z = x * fmaf(0.071354814f, t, 1.5957691f);
  float e = __expf(-z);
  return x * __builtin_amdgcn_rcpf(1.0f + e);
}

// ---- transpose+convert, all 18 weight matrices in ONE launch ----
// z 0..8: w1-group (K=DMODEL, N=DHID; z==0 shared, else expert z-1), grid (64,16)
// z 9..17: w2-group (K=DHID, N=DMODEL; z==9 shared, else expert z-10), grid reindexed to (16,64)
__global__ __launch_bounds__(256) void k_trans_all(const float* __restrict__ sw1,
                                                   const float* __restrict__ ew1,
                                                   const float* __restrict__ sw2,
                                                   const float* __restrict__ ew2,
                                                   unsigned short* __restrict__ w1t,
                                                   unsigned short* __restrict__ ew1t,
                                                   unsigned short* __restrict__ w2t,
                                                   unsigned short* __restrict__ ew2t) {
  const int zb = blockIdx.z;
  const float* in;
  unsigned short* out;
  int K, N, bx, by;
  if (zb < 9) {
    K = DMODEL; N = DHID;
    bx = blockIdx.x; by = blockIdx.y;          // 64 x 16
    if (zb == 0) { in = sw1; out = w1t; }
    else { in = ew1 + (size_t)(zb - 1) * K * N; out = ew1t + (size_t)(zb - 1) * N * K; }
  } else {
    K = DHID; N = DMODEL;
    const int id = blockIdx.y * 64 + blockIdx.x;  // 1024 blocks -> 16 x 64
    bx = id & 15; by = id >> 4;
    if (zb == 9) { in = sw2; out = w2t; }
    else { in = ew2 + (size_t)(zb - 10) * K * N; out = ew2t + (size_t)(zb - 10) * N * K; }
  }
  __shared__ float tile[64][65];
  const int n0 = bx * 64, k0 = by * 64;
  const int tx = threadIdx.x & 63, ty = threadIdx.x >> 6;
#pragma unroll
  for (int i = 0; i < 16; ++i) {
    const int k = ty * 16 + i;
    tile[k][tx] = in[(size_t)(k0 + k) * N + n0 + tx];
  }
  __syncthreads();
  const int sx = threadIdx.x & 7, sy = threadIdx.x >> 3;
#pragma unroll
  for (int j = 0; j < 2; ++j) {
    const int n = sy + j * 32;
    u32x4 v;
    v.x = (unsigned)f2bf(tile[sx * 8 + 0][n]) | ((unsigned)f2bf(tile[sx * 8 + 1][n]) << 16);
    v.y = (unsigned)f2bf(tile[sx * 8 + 2][n]) | ((unsigned)f2bf(tile[sx * 8 + 3][n]) << 16);
    v.z = (unsigned)f2bf(tile[sx * 8 + 4][n]) | ((unsigned)f2bf(tile[sx * 8 + 5][n]) << 16);
    v.w = (unsigned)f2bf(tile[sx * 8 + 6][n]) | ((unsigned)f2bf(tile[sx * 8 + 7][n]) << 16);
    *(u32x4*)&out[(size_t)(n0 + n) * K + k0 + sx * 8] = v;
  }
}

// ---------------- router: probs[e][t] + fused x->bf16 conversion ----------------
__global__ __launch_bounds__(256) void k_router(const float* __restrict__ x, const float* __restrict__ gw,
                                                const float* __restrict__ gb, const float* __restrict__ temp,
                                                float* __restrict__ probs, unsigned short* __restrict__ xb) {
  __shared__ float gws[DMODEL * NEXP];
  for (int i = threadIdx.x; i < DMODEL * NEXP; i += 256) gws[i] = gw[i];
  __syncthreads();
  const int wave = threadIdx.x >> 6, lane = threadIdx.x & 63;
  const int t = blockIdx.x * 4 + wave;
  const float* xr = x + (size_t)t * DMODEL;
  unsigned short* xw = xb + (size_t)t * DMODEL;
  float acc[NEXP];
#pragma unroll
  for (int e = 0; e < NEXP; ++e) acc[e] = 0.f;
  for (int d = lane; d < DMODEL; d += 64) {
    float xv = xr[d];
    xw[d] = f2bf(xv);
#pragma unroll
    for (int e = 0; e < NEXP; ++e) acc[e] += xv * gws[d * NEXP + e];
  }
#pragma unroll
  for (int off = 32; off >= 1; off >>= 1) {
#pragma unroll
    for (int e = 0; e < NEXP; ++e) acc[e] += __shfl_xor(acc[e], off);
  }
  if (lane == 0) {
    float st = fmaxf(temp[0], 0.1f);
    float m = -1e30f;
#pragma unroll
    for (int e = 0; e < NEXP; ++e) { acc[e] = (acc[e] + gb[e]) / st; m = fmaxf(m, acc[e]); }
    float s = 0.f;
#pragma unroll
    for (int e = 0; e < NEXP; ++e) { acc[e] = expf(acc[e] - m); s += acc[e]; }
    float inv = 1.f / s;
#pragma unroll
    for (int e = 0; e < NEXP; ++e) probs[(size_t)e * NTOK + t] = acc[e] * inv;
  }
}

// ------- exact top-512 per expert (radix select, tie -> lowest index) + slot map -------
// 1024 threads: 4x the scan parallelism of the old 256-thread version.
__global__ __launch_bounds__(1024) void k_topk(const float* __restrict__ probs, int* __restrict__ tok,
                                               float* __restrict__ scores, int* __restrict__ eqbuf,
                                               int* __restrict__ slot) {
  const int e = blockIdx.x;
  const float* p = probs + (size_t)e * NTOK;
  int* eq = eqbuf + (size_t)e * NTOK;
  int* sl = slot + (size_t)e * NTOK;
  __shared__ int hist[256];
  __shared__ unsigned sh_pref;
  __shared__ int sh_k, sh_gt, sh_eq, sh_cnt;
  const int tid = threadIdx.x;
  const int NTHR = 1024;
  for (int t = tid; t < NTOK; t += NTHR) sl[t] = -1;
  if (tid == 0) { sh_pref = 0u; sh_k = CAP; }
  __syncthreads();
  for (int pass = 3; pass >= 0; --pass) {
    if (tid < 256) hist[tid] = 0;
    __syncthreads();
    const unsigned pref = sh_pref;
    const int shift = pass * 8;
    for (int t = tid; t < NTOK; t += NTHR) {
      unsigned key = __float_as_uint(p[t]);
      bool cand = (pass == 3) || ((key >> (shift + 8)) == pref);
      if (cand) atomicAdd(&hist[(key >> shift) & 255], 1);
    }
    __syncthreads();
    if (tid == 0) {
      int k = sh_k;
      int d = 255;
      while (hist[d] < k) { k -= hist[d]; --d; }
      sh_k = k;
      sh_pref = (pref << 8) | (unsigned)d;
    }
    __syncthreads();
  }
  const unsigned Kstar = sh_pref;
  const int need_eq = sh_k;
  if (tid == 0) { sh_gt = 0; sh_eq = 0; }
  __syncthreads();
  for (int t = tid; t < NTOK; t += NTHR) {
    unsigned key = __float_as_uint(p[t]);
    if (key > Kstar) {
      int pos = atomicAdd(&sh_gt, 1);
      tok[e * CAP + pos] = t;
      scores[e * CAP + pos] = p[t];
      sl[t] = pos;
    } else if (key == Kstar) {
      int q = atomicAdd(&sh_eq, 1);
      eq[q] = t;
    }
  }
  __syncthreads();
  const int cg = sh_gt, ce = sh_eq;
  if (ce <= need_eq) {
    for (int j = tid; j < ce; j += NTHR) {
      tok[e * CAP + cg + j] = eq[j];
      scores[e * CAP + cg + j] = p[eq[j]];
      sl[eq[j]] = cg + j;
    }
  } else {
    int lo = 0, hi = NTOK - 1;
    while (lo < hi) {
      int mid = (lo + hi) >> 1;
      if (tid == 0) sh_cnt = 0;
      __syncthreads();
      for (int j = tid; j < ce; j += NTHR)
        if (eq[j] <= mid) atomicAdd(&sh_cnt, 1);
      __syncthreads();
      if (sh_cnt >= need_eq) hi = mid; else lo = mid + 1;
      __syncthreads();
    }
    if (tid == 0) sh_cnt = 0;
    __syncthreads();
    for (int j = tid; j < ce; j += NTHR) {
      if (eq[j] <= lo) {
        int pos = cg + atomicAdd(&sh_cnt, 1);
        tok[e * CAP + pos] = eq[j];
        scores[e * CAP + pos] = p[eq[j]];
        sl[eq[j]] = pos;
      }
    }
  }
}

// =====================================================================================
// m97-structure GEMM: 128x128, BK=64, 4 waves, single 32KB LDS, 4 blocks/CU.
// GATHER: A rows indirected via tok (fused token gather).
// MODE 0: bf16(gelu) LDS-bounce; MODE 3: dense score-scaled f32 partial store;
// MODE 4: shared output + fused routed combine from pe via slot map, nt stores.
//   MODE 4 reuses params: tok -> slot[NEXP][NTOK], scale -> pe[(e*2+kc)][CAP][DMODEL].
// =====================================================================================
template <int MODE, bool GATHER, bool NT>
__global__ __launch_bounds__(256, 4) void k_gemm(
    const unsigned short* __restrict__ A, const unsigned short* __restrict__ Bt,
    const float* __restrict__ bias, float* __restrict__ outF, unsigned short* __restrict__ outB,
    const int* __restrict__ tok, const float* __restrict__ scale,
    int M, int N, int Kloop, int LDK, int ksplit) {
  const int zb = blockIdx.z / ksplit;
  const int kc = blockIdx.z % ksplit;
  if (!GATHER) A += (size_t)zb * M * LDK;
  A += (size_t)kc * Kloop;
  Bt += (size_t)zb * N * LDK + (size_t)kc * Kloop;
  const float* bz = bias + (size_t)zb * N;

  const int gx = gridDim.x, gy = gridDim.y;
  const int nwg = gx * gy;
  const int id = blockIdx.x + blockIdx.y * gx;
  int bx, by;
  if ((gx & 7) == 0) {
    const int x = id & 7, c = id >> 3, H = gx >> 3;
    bx = x * H + (c % H);
    by = c / H;
  } else if ((nwg & 7) == 0) {
    const int q = nwg >> 3;
    const int sw = (id & 7) * q + (id >> 3);
    bx = sw % gx;
    by = sw / gx;
  } else {
    bx = blockIdx.x;
    by = blockIdx.y;
  }
  const int m0 = bx * 128, n0 = by * 128;

  const int tid = threadIdx.x, wave = tid >> 6, lane = tid & 63;
  const int wm = (wave >> 1) * 64, wn = (wave & 1) * 64;

  __shared__ alignas(16) unsigned short sh[128 * 128];
  unsigned short* As = sh;
  unsigned short* Bs = sh + 128 * 64;

  ffrag_t acc[4][4];
#pragma unroll
  for (int i = 0; i < 4; ++i)
#pragma unroll
    for (int j = 0; j < 4; ++j)
#pragma unroll
      for (int r = 0; r < 4; ++r) acc[i][j][r] = 0.f;

  int lb[4];
  const unsigned short* rowA[4];
  const unsigned short* rowB[4];
#pragma unroll
  for (int it = 0; it < 4; ++it) {
    int L = it * 256 + tid;
    int rr = L >> 3;
    int gg = (L & 7) ^ (rr & 7);
    lb[it] = (it * 256 + wave * 64) * 16;
    const unsigned short* ab =
        GATHER ? (A + (size_t)tok[zb * M + m0 + rr] * LDK) : (A + (size_t)(m0 + rr) * LDK);
    rowA[it] = ab + gg * 8;
    rowB[it] = Bt + (size_t)(n0 + rr) * LDK + gg * 8;
  }

  for (int kt = 0; kt < Kloop; kt += 64) {
#pragma unroll
    for (int it = 0; it < 4; ++it) {
      __builtin_amdgcn_global_load_lds(
          (const __attribute__((address_space(1))) unsigned int*)(rowA[it] + kt),
          (__attribute__((address_space(3))) unsigned int*)((char*)As + lb[it]), 16, 0, 0);
      __builtin_amdgcn_global_load_lds(
          (const __attribute__((address_space(1))) unsigned int*)(rowB[it] + kt),
          (__attribute__((address_space(3))) unsigned int*)((char*)Bs + lb[it]), 16, 0, 0);
    }
    __syncthreads();
#pragma unroll
    for (int kk = 0; kk < 2; ++kk) {
      bfrag_t af[4], bf[4];
      const int gl = kk * 4 + (lane >> 4);
#pragma unroll
      for (int mi = 0; mi < 4; ++mi) {
        int r = wm + mi * 16 + (lane & 15);
        af[mi] = *(const bfrag_t*)&As[r * 64 + ((gl ^ (r & 7)) * 8)];
      }
#pragma unroll
      for (int ni = 0; ni < 4; ++ni) {
        int r = wn + ni * 16 + (lane & 15);
        bf[ni] = *(const bfrag_t*)&Bs[r * 64 + ((gl ^ (r & 7)) * 8)];
      }
#pragma unroll
      for (int mi = 0; mi < 4; ++mi)
#pragma unroll
        for (int ni = 0; ni < 4; ++ni)
          acc[mi][ni] = __builtin_amdgcn_mfma_f32_16x16x32_bf16(af[mi], bf[ni], acc[mi][ni], 0, 0, 0);
    }
    __syncthreads();
  }

  const int rsub = (lane >> 4) * 4, cs = lane & 15;
  if (MODE == 0) {
    float bv[4];
#pragma unroll
    for (int ni = 0; ni < 4; ++ni) bv[ni] = bz[n0 + wn + ni * 16 + cs];
#pragma unroll
    for (int mi = 0; mi < 4; ++mi)
#pragma unroll
      for (int ni = 0; ni < 4; ++ni)
#pragma unroll
        for (int r = 0; r < 4; ++r) {
          float v = acc[mi][ni][r] + bv[ni];
          sh[(wm + mi * 16 + rsub + r) * 128 + (wn + ni * 16 + cs)] = f2bf(gelu_fast(v));
        }
    __syncthreads();
    const int seg = tid & 15, rw = tid >> 4;
#pragma unroll
    for (int rep = 0; rep < 8; ++rep) {
      const int row = rep * 16 + rw;
      u32x4 v = *(const u32x4*)&sh[row * 128 + seg * 8];
      u32x4* dst = (u32x4*)&outB[((size_t)zb * M + m0 + row) * N + n0 + seg * 8];
      if (NT)
        __builtin_nontemporal_store(v, dst);
      else
        *dst = v;
    }
  } else if (MODE == 3) {  // dense score-scaled partial store (cached)
    float* po = outF + (size_t)blockIdx.z * M * N;
#pragma unroll
    for (int ni = 0; ni < 4; ++ni) {
      const int n = n0 + wn + ni * 16 + cs;
      const float bv = (kc == 0) ? bz[n] : 0.f;
#pragma unroll
      for (int mi = 0; mi < 4; ++mi)
#pragma unroll
        for (int r = 0; r < 4; ++r) {
          const int m = m0 + wm + mi * 16 + rsub + r;
          const float s = scale[zb * M + m];
          po[(size_t)m * N + n] = (acc[mi][ni][r] + bv) * s;
        }
    }
  } else {  // MODE 4: shared + fused routed combine, nt stores
    const int* slot = tok;
    const float* pe = scale;
    float bv[4];
#pragma unroll
    for (int ni = 0; ni < 4; ++ni) bv[ni] = bz[n0 + wn + ni * 16 + cs];
#pragma unroll
    for (int mi = 0; mi < 4; ++mi) {
#pragma unroll
      for (int r = 0; r < 4; ++r) {
        const int m = m0 + wm + mi * 16 + rsub + r;
        float ex[4] = {0.f, 0.f, 0.f, 0.f};
#pragma unroll
        for (int e = 0; e < NEXP; ++e) {
          const int sl = slot[(size_t)e * NTOK + m];
          if (sl >= 0) {
            const float* p0 = pe + ((size_t)(e * 2 + 0) * CAP + sl) * DMODEL;
            const float* p1 = pe + ((size_t)(e * 2 + 1) * CAP + sl) * DMODEL;
#pragma unroll
            for (int ni = 0; ni < 4; ++ni) {
              const int n = n0 + wn + ni * 16 + cs;
              ex[ni] += p0[n] + p1[n];
            }
          }
        }
#pragma unroll
        for (int ni = 0; ni < 4; ++ni) {
          const int n = n0 + wn + ni * 16 + cs;
          __builtin_nontemporal_store(acc[mi][ni][r] + bv[ni] + ex[ni],
                                      &outF[(size_t)m * N + n]);
        }
      }
    }
  }
}

extern "C" void kernel_launch(void* const* d_in, const int* in_sizes, int n_in,
                              void* d_out, int out_size, void* d_ws, size_t ws_size,
                              hipStream_t stream) {
  const float* x      = (const float*)d_in[0];
  const float* gate_w = (const float*)d_in[1];
  const float* gate_b = (const float*)d_in[2];
  const float* temp   = (const float*)d_in[3];
  const float* sw1    = (const float*)d_in[4];
  const float* sb1    = (const float*)d_in[5];
  const float* sw2    = (const float*)d_in[6];
  const float* sb2    = (const float*)d_in[7];
  const float* ew1    = (const float*)d_in[8];
  const float* eb1    = (const float*)d_in[9];
  const float* ew2    = (const float*)d_in[10];
  const float* eb2    = (const float*)d_in[11];
  float* out = (float*)d_out;

  char* ws = (char*)d_ws;
  size_t o = 0;
  auto take = [&](size_t bytes) { char* p = ws + o; o += (bytes + 255) & ~(size_t)255; return p; };
  unsigned short* x_bf = (unsigned short*)take((size_t)NTOK * DMODEL * 2);
  unsigned short* w1t  = (unsigned short*)take((size_t)DMODEL * DHID * 2);
  unsigned short* w2t  = (unsigned short*)take((size_t)DHID * DMODEL * 2);
  unsigned short* ew1t = (unsigned short*)take((size_t)NEXP * DMODEL * DHID * 2);
  unsigned short* ew2t = (unsigned short*)take((size_t)NEXP * DHID * DMODEL * 2);
  float* probs         = (float*)take((size_t)NEXP * NTOK * 4);
  int* tok             = (int*)take((size_t)NEXP * CAP * 4);
  float* scores        = (float*)take((size_t)NEXP * CAP * 4);
  int* eqbuf           = (int*)take((size_t)NEXP * NTOK * 4);
  int* slot            = (int*)take((size_t)NEXP * NTOK * 4);
  float* pe            = (float*)take((size_t)NEXP * 2 * CAP * DMODEL * 4);
  unsigned short* he   = (unsigned short*)take((size_t)NEXP * CAP * DHID * 2);
  unsigned short* hs   = (unsigned short*)take((size_t)NTOK * DHID * 2);

  // prep: all 18 weight transposes in one launch; x conversion fused into router
  k_trans_all<<<dim3(64, 16, 18), 256, 0, stream>>>(sw1, ew1, sw2, ew2, w1t, ew1t, w2t, ew2t);

  // router (+ x->bf16) + top-k (+ slot map)
  k_router<<<NTOK / 4, 256, 0, stream>>>(x, gate_w, gate_b, temp, probs, x_bf);
  k_topk<<<NEXP, 1024, 0, stream>>>(probs, tok, scores, eqbuf, slot);

  // shared FFN-1 (cached stores — NT refuted on this path)
  k_gemm<0, false, false><<<dim3(128, 32, 1), 256, 0, stream>>>(
      x_bf, w1t, sb1, nullptr, hs, nullptr, nullptr, NTOK, DHID, DMODEL, DMODEL, 1);

  // routed experts: FFN-1 with fused gather; FFN-2 dense scaled partials (no atomics)
  k_gemm<0, true, false><<<dim3(4, 32, NEXP), 256, 0, stream>>>(
      x_bf, ew1t, eb1, nullptr, he, tok, nullptr, CAP, DHID, DMODEL, DMODEL, 1);
  k_gemm<3, false, false><<<dim3(4, 8, NEXP * 2), 256, 0, stream>>>(
      he, ew2t, eb2, pe, nullptr, nullptr, scores, CAP, DMODEL, DHID / 2, DHID, 2);

  // shared FFN-2 with fused routed combine (reads pe via slot map), nt out stores
  k_gemm<4, false, true><<<dim3(128, 8, 1), 256, 0, stream>>>(
      hs, w2t, sb2, out, nullptr, slot, pe, NTOK, DMODEL, DHID, DHID, 1);
}